// Round 3
// baseline (207.878 us; speedup 1.0000x reference)
//
#include <hip/hip_runtime.h>

#define LTAG 64
#define NEGV -10000.0f
#define L2E 1.4426950408889634f
#define LN2 0.6931471805599453f

typedef float vfloat2 __attribute__((ext_vector_type(2)));

// v_exp_f32: 2^x ; v_log_f32: log2(x)
__device__ __forceinline__ float exp2_fast(float x) { return __builtin_amdgcn_exp2f(x); }
__device__ __forceinline__ float log2_fast(float x) { return __builtin_amdgcn_logf(x); }

__device__ __forceinline__ float readlane_f(float v, int lane) {
    return __int_as_float(__builtin_amdgcn_readlane(__float_as_int(v), lane));
}

// One wave (64 lanes) per batch element. lane = next-tag index n.
//
// Exp-domain recurrence: state A[n] = exp2(alpha[n]*L2E - SH), SH wave-uniform.
//   A'[n] = (sum_p A[p] * Etr[p][n]) * g[n],  g[n] = exp2(x_t[n]*L2E + c2[n])
// with Etr[p][n] = exp2(trans[p][n]*L2E - c2[n]) held in VGPRs (constant,
// packed float2 pairs feeding v_pk_fma_f32).
//
// Per-step serial chain is ONLY: ds_write(A) -> 16x uniform ds_read_b128
// (broadcast, bank-conflict-free) -> 32 pk_fma -> reduce -> *g.
//   - g's exp2 is issued at substep start from an x prefetched 4 full steps
//     earlier (distance-4 ring, consumed at substep granularity -> no
//     group-top vmcnt stall; round-2 lesson).
//   - no readlanes on the chain (SGPR-write hazard; round-2 lesson);
//     readlanes appear only in the every-4-steps rescale.
//   - single wave per block + in-order same-wave DS pipe => NO barriers
//     (pattern validated by round-2 pass).
//
// Exact power-of-2 rescale every 4 steps keeps A in fp32 range (growth
// <~2^19/step worst case; sampled-max spread ~2^35; 35+4*19 < 127).
//
// Column B (lane 0) is fully masked (-10000): g[B] == 0 exactly, so A[B] == 0
// throughout. Its true final value is recovered analytically: lane 0's Etr
// column is all-ones (c2_B = -10000*L2E), so its per-step matvec result
// s_B = sum_p A[p]; the last step's (s, x, SH) give
// alpha_T[B] = (log2 s_B + x*L2E + c2_B + SH)*LN2.
__global__ __launch_bounds__(64) void crf_forward_kernel(
    const float* __restrict__ X, const float* __restrict__ trans,
    float* __restrict__ out, int T) {
    const int lane = threadIdx.x;
    const int b = blockIdx.x;
    const float* xb = X + (size_t)b * T * LTAG + lane;

    __shared__ __align__(16) float e_sh[LTAG];

    // ---- precompute Etr column for this lane (once), packed float2 ----
    vfloat2 etr2[LTAG / 2];
    float c2 = -3.0e38f;
#pragma unroll
    for (int i = 0; i < LTAG / 2; ++i) {
        const float t0 = trans[(2 * i + 0) * LTAG + lane] * L2E;
        const float t1 = trans[(2 * i + 1) * LTAG + lane] * L2E;
        c2 = fmaxf(c2, fmaxf(t0, t1));
        etr2[i].x = t0;
        etr2[i].y = t1;
    }
#pragma unroll
    for (int i = 0; i < LTAG / 2; ++i) {
        etr2[i].x = exp2_fast(etr2[i].x - c2);
        etr2[i].y = exp2_fast(etr2[i].y - c2);
    }

    // ---- init: alpha = NEG except tag B (lane 0) = 0 ----
    float A = (lane == 0) ? 1.0f : 0.0f;
    float SH = 0.0f;
    float sB = 1.0f, xB = 0.0f, shB = 0.0f;  // lane-0 (tag B) fixup state

    // ---- x prefetch ring, distance 4 (use/reload at substep granularity) --
    float xr[4];
#pragma unroll
    for (int i = 0; i < 4; ++i) xr[i] = xb[(size_t)i * LTAG];

    e_sh[lane] = A;  // prologue ds_write (same-wave order covers first reads)

    for (int t = 0; t < T; t += 4) {
#pragma unroll
        for (int u = 0; u < 4; ++u) {
            const float xcur = xr[u];  // loaded exactly 4 steps ago
            int tpf = t + u + 4;
            tpf = tpf < T ? tpf : T - 1;
            xr[u] = xb[(size_t)tpf * LTAG];

            // off the serial chain: exp2 latency hides under the matvec
            const float g = exp2_fast(fmaf(xcur, L2E, c2));

            // ---- uniform LDS broadcast reads (prev substep's ds_write) ----
            // bank-conflict-free; compiler emits fine-grained lgkmcnt waits
            vfloat2 ac0 = {0.f, 0.f}, ac1 = {0.f, 0.f};
            vfloat2 ac2 = {0.f, 0.f}, ac3 = {0.f, 0.f};
#pragma unroll
            for (int i = 0; i < LTAG / 8; ++i) {
                const float4 ev0 = *(const float4*)(e_sh + 8 * i);
                const float4 ev1 = *(const float4*)(e_sh + 8 * i + 4);
                const vfloat2 e0 = {ev0.x, ev0.y};
                const vfloat2 e1 = {ev0.z, ev0.w};
                const vfloat2 e2 = {ev1.x, ev1.y};
                const vfloat2 e3 = {ev1.z, ev1.w};
                ac0 = __builtin_elementwise_fma(e0, etr2[4 * i + 0], ac0);
                ac1 = __builtin_elementwise_fma(e1, etr2[4 * i + 1], ac1);
                ac2 = __builtin_elementwise_fma(e2, etr2[4 * i + 2], ac2);
                ac3 = __builtin_elementwise_fma(e3, etr2[4 * i + 3], ac3);
            }
            const vfloat2 aa = (ac0 + ac1) + (ac2 + ac3);
            const float s = aa.x + aa.y;

            sB = s; xB = xcur; shB = SH;  // last-step save for lane-0 fixup
            A = s * g;

            if (u == 3) {
                // ---- wave-uniform EXACT power-of-2 rescale, every 4 steps --
                // samples avoid lane 0 (tag B: exactly 0 in exp domain);
                // readlane hazards amortized 1/4
                float mm = fmaxf(readlane_f(A, 2), readlane_f(A, 19));
                mm = fmaxf(mm, readlane_f(A, 28));
                mm = fmaxf(mm, fmaxf(readlane_f(A, 37), readlane_f(A, 53)));
                int eb2 = (__float_as_int(mm) >> 23) & 0xff;  // biased exp
                eb2 = eb2 < 1 ? 1 : eb2;                      // safety clamp
                A *= __int_as_float((254 - eb2) << 23);  // *= 2^(127-eb), exact
                SH += (float)(eb2 - 127);
            }

            e_sh[lane] = A;  // ds_write for NEXT substep's broadcast
        }
    }

    float res;
    if (lane == 0) {
        // tag B analytic fixup (see header comment)
        res = (log2_fast(sB) + fmaf(xB, L2E, c2) + shB) * LN2;
    } else {
        res = (log2_fast(A) + SH) * LN2;
    }
    out[b * LTAG + lane] = res;
}

extern "C" void kernel_launch(void* const* d_in, const int* in_sizes, int n_in,
                              void* d_out, int out_size, void* d_ws, size_t ws_size,
                              hipStream_t stream) {
    const float* X = (const float*)d_in[0];
    const float* trans = (const float*)d_in[1];
    float* out = (float*)d_out;

    const int B = out_size / LTAG;           // 256
    const int T = in_sizes[0] / (B * LTAG);  // 512

    crf_forward_kernel<<<B, LTAG, 0, stream>>>(X, trans, out, T);
}

// Round 4
// 180.544 us; speedup vs baseline: 1.1514x; 1.1514x over previous
//
#include <hip/hip_runtime.h>

#define LTAG 64
#define NEGV -10000.0f
#define L2E 1.4426950408889634f
#define LN2 0.6931471805599453f

// v_exp_f32: 2^x ; v_log_f32: log2(x)
__device__ __forceinline__ float exp2_fast(float x) { return __builtin_amdgcn_exp2f(x); }
__device__ __forceinline__ float log2_fast(float x) { return __builtin_amdgcn_logf(x); }

__device__ __forceinline__ float readlane_f(float v, int lane) {
    return __int_as_float(__builtin_amdgcn_readlane(__float_as_int(v), lane));
}

// One wave (64 lanes) per batch element. lane = next-tag index n.
//
// Exp-domain recurrence: state A[n] = exp2(alpha[n]*L2E - SH), SH wave-uniform.
//   A'[n] = (sum_p A[p] * Etr[p][n]) * g[n],  g[n] = exp2(x_t[n]*L2E + c2[n])
// with Etr[p][n] = exp2(trans[p][n]*L2E - c2[n]) held in 64 VGPRs (constant).
//
// ROUND-4 STRUCTURE: the per-step all-to-all broadcast of A is done ENTIRELY
// in the VALU — no LDS on the serial chain (round-3 counters: VALUBusy 6%,
// ~727 cy/step all stalled in the ds_write->ds_read_b128 round trip).
//   phase 1: 64x v_readlane  A -> wave-uniform scalars (batched, so the
//            VALU-writes-SGPR -> VALU-reads-SGPR hazard is paid ~once,
//            not per pair — round-2 lesson)
//   phase 2: 64x v_fmac with SGPR broadcast operand (1 SGPR/VALU op: legal),
//            4 independent accumulator chains
// Chain is pure VALU issue: ~310-350 cy/step predicted.
//
// g's exp2 comes from an x prefetched 4 full steps earlier (distance-4 ring,
// consumed per-substep; no group-top vmcnt stall — round-2 lesson).
//
// Exact power-of-2 rescale every 4 steps keeps A in fp32 range (growth
// <~2^19/step worst case; sampled-max spread ~2^35; 35+4*19 < 127).
//
// Column B (lane 0) is fully masked (-10000): g[B] == 0 exactly, so A[B] == 0
// throughout. Its true final value is recovered analytically: lane 0's Etr
// column is all-ones (c2_B = -10000*L2E), so its per-step matvec result
// s_B = sum_p A[p]; the last step's (s, x, SH) give
// alpha_T[B] = (log2 s_B + x*L2E + c2_B + SH)*LN2.
__global__ __launch_bounds__(64) void crf_forward_kernel(
    const float* __restrict__ X, const float* __restrict__ trans,
    float* __restrict__ out, int T) {
    const int lane = threadIdx.x;
    const int b = blockIdx.x;
    const float* xb = X + (size_t)b * T * LTAG + lane;

    // ---- precompute Etr column for this lane (once) ----
    float etr[LTAG];
    float c2 = -3.0e38f;
#pragma unroll
    for (int p = 0; p < LTAG; ++p) {
        etr[p] = trans[p * LTAG + lane] * L2E;
        c2 = fmaxf(c2, etr[p]);
    }
#pragma unroll
    for (int p = 0; p < LTAG; ++p) etr[p] = exp2_fast(etr[p] - c2);

    // ---- init: alpha = NEG except tag B (lane 0) = 0 ----
    float A = (lane == 0) ? 1.0f : 0.0f;
    float SH = 0.0f;
    float sB = 1.0f, xB = 0.0f, shB = 0.0f;  // lane-0 (tag B) fixup state

    // ---- x prefetch ring, distance 4 (use/reload at substep granularity) --
    float xr[4];
#pragma unroll
    for (int i = 0; i < 4; ++i) xr[i] = xb[(size_t)i * LTAG];

    for (int t = 0; t < T; t += 4) {
#pragma unroll
        for (int u = 0; u < 4; ++u) {
            const float xcur = xr[u];  // loaded exactly 4 steps ago
            int tpf = t + u + 4;
            tpf = tpf < T ? tpf : T - 1;
            xr[u] = xb[(size_t)tpf * LTAG];

            // off the serial chain: exp2 latency hides under the broadcast
            const float g = exp2_fast(fmaf(xcur, L2E, c2));

            // ---- phase 1: batched readlane broadcast (A -> uniform) ----
            float ub[LTAG];
#pragma unroll
            for (int p = 0; p < LTAG; ++p) ub[p] = readlane_f(A, p);

            // ---- phase 2: 64 fmacs, SGPR broadcast * VGPR etr ----
            float s0 = 0.f, s1 = 0.f, s2 = 0.f, s3 = 0.f;
#pragma unroll
            for (int p = 0; p < LTAG; p += 4) {
                s0 = fmaf(ub[p + 0], etr[p + 0], s0);
                s1 = fmaf(ub[p + 1], etr[p + 1], s1);
                s2 = fmaf(ub[p + 2], etr[p + 2], s2);
                s3 = fmaf(ub[p + 3], etr[p + 3], s3);
            }
            const float s = (s0 + s1) + (s2 + s3);

            sB = s; xB = xcur; shB = SH;  // last-step save for lane-0 fixup
            A = s * g;

            if (u == 3) {
                // ---- wave-uniform EXACT power-of-2 rescale, every 4 steps --
                // samples avoid lane 0 (tag B: exactly 0 in exp domain)
                float mm = fmaxf(readlane_f(A, 2), readlane_f(A, 19));
                mm = fmaxf(mm, readlane_f(A, 28));
                mm = fmaxf(mm, fmaxf(readlane_f(A, 37), readlane_f(A, 53)));
                int eb2 = (__float_as_int(mm) >> 23) & 0xff;  // biased exp
                eb2 = eb2 < 1 ? 1 : eb2;                      // safety clamp
                A *= __int_as_float((254 - eb2) << 23);  // *= 2^(127-eb), exact
                SH += (float)(eb2 - 127);
            }
        }
    }

    float res;
    if (lane == 0) {
        // tag B analytic fixup (see header comment)
        res = (log2_fast(sB) + fmaf(xB, L2E, c2) + shB) * LN2;
    } else {
        res = (log2_fast(A) + SH) * LN2;
    }
    out[b * LTAG + lane] = res;
}

extern "C" void kernel_launch(void* const* d_in, const int* in_sizes, int n_in,
                              void* d_out, int out_size, void* d_ws, size_t ws_size,
                              hipStream_t stream) {
    const float* X = (const float*)d_in[0];
    const float* trans = (const float*)d_in[1];
    float* out = (float*)d_out;

    const int B = out_size / LTAG;           // 256
    const int T = in_sizes[0] / (B * LTAG);  // 512

    crf_forward_kernel<<<B, LTAG, 0, stream>>>(X, trans, out, T);
}